// Round 6
// baseline (620.036 us; speedup 1.0000x reference)
//
#include <hip/hip_runtime.h>
#include <hip/hip_bf16.h>
#include <stdint.h>

#define BB 16384
#define ZZ 64
#define DD 66
#define NB 4     // batch rows per wave
#define WPB 4    // waves per block

// ---- ws float offsets (filled by prep kernel every launch) ----
#define OFF_SVMU 0        // [66][64] float2 (mult_u, sqrt(var_u)) -> 8448 floats
#define OFF_C0U  8448     // 64 : -0.5*sum_d(1+lv-var) per z
#define OFF_MG   8512     // 64
#define OFF_SVG  8576     // 64
#define OFF_C0G  8640     // 1

// Fold exps/constants once per launch (1 small block).
__global__ void prep_kernel(const float* __restrict__ mult_u, const float* __restrict__ logvar_u,
                            const float* __restrict__ mult_g, const float* __restrict__ logvar_g,
                            float* __restrict__ ws) {
  const int t = threadIdx.x;
  for (int i = t; i < DD*ZZ; i += 256) {
    ws[OFF_SVMU + 2*i]     = mult_u[i];
    ws[OFF_SVMU + 2*i + 1] = __expf(0.5f * logvar_u[i]);
  }
  if (t < ZZ) {
    float s = 0.f;
    for (int d = 0; d < DD; ++d) {
      const float lv = logvar_u[d*ZZ + t];
      s += 1.f + lv - __expf(lv);
    }
    ws[OFF_C0U + t] = -0.5f * s;
    ws[OFF_MG  + t] = mult_g[t];
    ws[OFF_SVG + t] = __expf(0.5f * logvar_g[t]);
  }
  if (t == 0) {
    float s = 0.f;
    for (int z = 0; z < ZZ; ++z) {
      const float lv = logvar_g[z];
      s += 1.f + lv - __expf(lv);
    }
    ws[OFF_C0G] = -0.5f * s;
  }
}

// Main: lane = z; wave w handles batch rows b0..b0+NB-1. No cross-lane ops.
__global__ __launch_bounds__(256, 2)
void disrnn_main(const float* __restrict__ latents, const float* __restrict__ obs,
                 const float* __restrict__ noise_u, const float* __restrict__ noise_g,
                 const float* __restrict__ z0, const float* __restrict__ W1,
                 const float* __restrict__ b1, const float* __restrict__ W2,
                 const float* __restrict__ b2, const float* __restrict__ W3,
                 const float* __restrict__ b3,
                 const float* __restrict__ ws, const int* __restrict__ t0p,
                 float* __restrict__ out) {
  float* out_zt = out + BB*2;
  float* out_kg = out + BB*2 + BB*ZZ;
  float* out_ku = out + BB*2 + BB*ZZ + BB;

  __shared__ float x_lds[WPB][NB][68];  // x rows (66 used)
  __shared__ float red[WPB][NB][64];    // tg^2 for kld_g

  const int tid  = threadIdx.x;
  const int w    = tid >> 6;
  const int lane = tid & 63;
  const int b0   = (blockIdx.x * WPB + w) * NB;
  const int t0   = *t0p;

  const float c0u_l = ws[OFF_C0U + lane];
  const float mg_l  = ws[OFF_MG + lane];
  const float svg_l = ws[OFF_SVG + lane];
  const float c0g   = ws[OFF_C0G];
  const float b3_0  = b3[lane*2];
  const float b3_1  = b3[lane*2 + 1];
  const float2* __restrict__ svmu = (const float2*)(ws + OFF_SVMU);

  // stage x rows: x = [lat | obs]
#pragma unroll
  for (int i = 0; i < NB; ++i) {
    x_lds[w][i][lane] = t0 ? z0[lane] : latents[(b0 + i)*ZZ + lane];
    if (lane < 2) x_lds[w][i][ZZ + lane] = obs[(b0 + i)*2 + lane];
  }
  __syncthreads();

  float acc[NB][16], kacc[NB];
  {
    const float4* bp = reinterpret_cast<const float4*>(b1 + lane*16);
    float b1r[16];
#pragma unroll
    for (int q = 0; q < 4; ++q) {
      const float4 v = bp[q];
      b1r[4*q] = v.x; b1r[4*q+1] = v.y; b1r[4*q+2] = v.z; b1r[4*q+3] = v.w;
    }
#pragma unroll
    for (int i = 0; i < NB; ++i) {
      kacc[i] = 0.f;
#pragma unroll
      for (int h = 0; h < 16; ++h) acc[i][h] = b1r[h];
    }
  }

  // ---- layer 1 over all 66 input dims ----
  for (int d = 0; d < DD; ++d) {
    const float2 sm = svmu[d*ZZ + lane];
    const float4* wp = reinterpret_cast<const float4*>(W1 + (lane*DD + d)*16);
    float wv[16];
#pragma unroll
    for (int q = 0; q < 4; ++q) {
      const float4 v = wp[q];
      wv[4*q] = v.x; wv[4*q+1] = v.y; wv[4*q+2] = v.z; wv[4*q+3] = v.w;
    }
#pragma unroll
    for (int i = 0; i < NB; ++i) {
      const float xv   = x_lds[w][i][d];           // broadcast read
      const float mean = xv * sm.x;
      const float nv   = noise_u[((b0 + i)*DD + d)*ZZ + lane];
      const float xt   = fmaf(nv, sm.y, mean);
      kacc[i] = fmaf(mean, mean, kacc[i]);
#pragma unroll
      for (int h = 0; h < 16; ++h) acc[i][h] = fmaf(xt, wv[h], acc[i][h]);
    }
  }

  // ---- layer 2 ----
  float h2[NB][16];
  {
    const float4* bp = reinterpret_cast<const float4*>(b2 + lane*16);
    float b2r[16];
#pragma unroll
    for (int q = 0; q < 4; ++q) {
      const float4 v = bp[q];
      b2r[4*q] = v.x; b2r[4*q+1] = v.y; b2r[4*q+2] = v.z; b2r[4*q+3] = v.w;
    }
#pragma unroll
    for (int i = 0; i < NB; ++i) {
#pragma unroll
      for (int h = 0; h < 16; ++h) acc[i][h] = fmaxf(acc[i][h], 0.f);
#pragma unroll
      for (int k = 0; k < 16; ++k) h2[i][k] = b2r[k];
    }
  }
  for (int h = 0; h < 16; ++h) {
    const float4* wp = reinterpret_cast<const float4*>(W2 + (lane*16 + h)*16);
    float wv[16];
#pragma unroll
    for (int q = 0; q < 4; ++q) {
      const float4 v = wp[q];
      wv[4*q] = v.x; wv[4*q+1] = v.y; wv[4*q+2] = v.z; wv[4*q+3] = v.w;
    }
#pragma unroll
    for (int i = 0; i < NB; ++i) {
      const float hv = acc[i][h];
#pragma unroll
      for (int k = 0; k < 16; ++k) h2[i][k] = fmaf(hv, wv[k], h2[i][k]);
    }
  }

  // ---- layer 3 + gate + kld/z_tilde outputs ----
  float w3r[32];
  {
    const float4* wp = reinterpret_cast<const float4*>(W3 + lane*32);
#pragma unroll
    for (int q = 0; q < 8; ++q) {
      const float4 v = wp[q];
      w3r[4*q] = v.x; w3r[4*q+1] = v.y; w3r[4*q+2] = v.z; w3r[4*q+3] = v.w;
    }
  }
#pragma unroll
  for (int i = 0; i < NB; ++i) {
    const int b = b0 + i;
    float o0 = b3_0, o1 = b3_1;
#pragma unroll
    for (int k = 0; k < 16; ++k) {
      const float hv = fmaxf(h2[i][k], 0.f);
      o0 = fmaf(hv, w3r[2*k], o0);
      o1 = fmaf(hv, w3r[2*k + 1], o1);
    }
    const float xl = x_lds[w][i][lane];
    const float wg = 1.f / (1.f + __expf(-o1));
    const float nl = fmaf(wg, o0 - xl, xl);        // (1-w)*lat + u*w
    const float tg = mg_l * nl;
    const float zt = fmaf(noise_g[b*ZZ + lane], svg_l, tg);
    out_zt[b*ZZ + lane] = zt;
    out_ku[b*ZZ + lane] = fmaf(0.5f, kacc[i], c0u_l);
    red[w][i][lane] = tg * tg;
  }
  __syncthreads();
  if (lane < NB) {
    float s = 0.f;
    for (int z = 0; z < ZZ; ++z) s += red[w][lane][z];
    out_kg[b0 + lane] = fmaf(0.5f, s, c0g);
  }
}

// Choice MLP: one wave per batch row, LDS staging, no cross-lane ops.
__global__ __launch_bounds__(256, 2)
void choice_kernel(const float* __restrict__ Wc1, const float* __restrict__ bc1,
                   const float* __restrict__ Wc2, const float* __restrict__ bc2,
                   const float* __restrict__ Wc3, const float* __restrict__ bc3,
                   float* __restrict__ out) {
  const float* zt_in = out + BB*2;   // z_tilde written by disrnn_main
  float* out_y = out;

  __shared__ float zl[WPB][64];
  __shared__ float y1[WPB][32];
  __shared__ float y2[WPB][32];

  const int tid  = threadIdx.x;
  const int w    = tid >> 6;
  const int lane = tid & 63;
  const int b    = blockIdx.x * WPB + w;

  zl[w][lane] = zt_in[b*ZZ + lane];
  __syncthreads();
  if (lane < 32) {
    float a = bc1[lane];
    for (int z = 0; z < 64; ++z) a = fmaf(zl[w][z], Wc1[z*32 + lane], a);
    y1[w][lane] = fmaxf(a, 0.f);
  }
  __syncthreads();
  if (lane < 32) {
    float a = bc2[lane];
    for (int h = 0; h < 32; ++h) a = fmaf(y1[w][h], Wc2[h*32 + lane], a);
    y2[w][lane] = fmaxf(a, 0.f);
  }
  __syncthreads();
  if (lane == 0) {
    float s0 = bc3[0], s1 = bc3[1];
    for (int k = 0; k < 32; ++k) {
      s0 = fmaf(y2[w][k], Wc3[2*k], s0);
      s1 = fmaf(y2[w][k], Wc3[2*k + 1], s1);
    }
    out_y[b*2]     = s0;
    out_y[b*2 + 1] = s1;
  }
}

extern "C" void kernel_launch(void* const* d_in, const int* in_sizes, int n_in,
                              void* d_out, int out_size, void* d_ws, size_t ws_size,
                              hipStream_t stream) {
  const float* latents  = (const float*)d_in[0];
  const float* obs      = (const float*)d_in[1];
  const float* noise_u  = (const float*)d_in[2];
  const float* noise_g  = (const float*)d_in[3];
  const float* z0       = (const float*)d_in[4];
  const float* mult_u   = (const float*)d_in[5];
  const float* logvar_u = (const float*)d_in[6];
  const float* mult_g   = (const float*)d_in[7];
  const float* logvar_g = (const float*)d_in[8];
  const float* W1       = (const float*)d_in[9];
  const float* b1       = (const float*)d_in[10];
  const float* W2       = (const float*)d_in[11];
  const float* b2       = (const float*)d_in[12];
  const float* W3       = (const float*)d_in[13];
  const float* b3       = (const float*)d_in[14];
  const float* Wc1      = (const float*)d_in[15];
  const float* bc1      = (const float*)d_in[16];
  const float* Wc2      = (const float*)d_in[17];
  const float* bc2      = (const float*)d_in[18];
  const float* Wc3      = (const float*)d_in[19];
  const float* bc3      = (const float*)d_in[20];
  const int*  t0p       = (const int*)d_in[21];
  float* ws = (float*)d_ws;
  float* outp = (float*)d_out;

  prep_kernel<<<1, 256, 0, stream>>>(mult_u, logvar_u, mult_g, logvar_g, ws);
  disrnn_main<<<BB/(WPB*NB), 256, 0, stream>>>(latents, obs, noise_u, noise_g, z0,
                                               W1, b1, W2, b2, W3, b3,
                                               ws, t0p, outp);
  choice_kernel<<<BB/WPB, 256, 0, stream>>>(Wc1, bc1, Wc2, bc2, Wc3, bc3, outp);
}